// Round 8
// baseline (1037.827 us; speedup 1.0000x reference)
//
#include <hip/hip_runtime.h>

#define HW   16384
#define CC   256
#define OT   32      // out-channel tile per block (fp32 path)
#define NT   512     // column tile per block (fp32 path)
#define KB   8       // k-chunk (fp32 path)

typedef float          f32x4  __attribute__((ext_vector_type(4)));
typedef short          bf16x8 __attribute__((ext_vector_type(8)));
typedef unsigned short u16x8  __attribute__((ext_vector_type(8)));

__device__ inline unsigned short f2bf(float x) {     // RNE float->bf16
    unsigned u = __float_as_uint(x);
    u += 0x7FFFu + ((u >> 16) & 1u);
    return (unsigned short)(u >> 16);
}
__device__ inline float bf2f(unsigned short h) {
    return __uint_as_float(((unsigned)h) << 16);
}

// ---------------------------------------------------------------------------
// GEMM1 (fp32, bit-exact h): h = W_proj * x, fused BN stats.
// W chunk-loads hoisted ABOVE the ds_read/FMA loop: one lgkmcnt(0) drain for
// the s_load batch per chunk, then a pure-ds_read inner loop (fine-grained
// lgkmcnt(N) works again). FMA order identical to round 5.
// ---------------------------------------------------------------------------
__global__ __launch_bounds__(256)
void gu_gemm1(const float* __restrict__ x, const float* __restrict__ Wp,
              float* __restrict__ h, float* __restrict__ psum,
              float* __restrict__ psumsq)
{
    __shared__ float xs[2][KB][NT];

    const int t  = threadIdx.x;
    const int tx = t & 63, ty = t >> 6;
    const int tyu = __builtin_amdgcn_readfirstlane(ty);
    const int o0 = blockIdx.y * OT;
    const int n0 = blockIdx.x * NT;
    const int b  = n0 >> 14;
    const int hw0 = n0 & (HW - 1);
    const float* xb = x + ((size_t)b * CC) * HW + hw0;
    const float* Wb = Wp + (size_t)(o0 + tyu * 8) * CC;

    float4 pf[4];
    #pragma unroll
    for (int q = 0; q < 4; ++q) {
        int f = t + 256 * q; int k = f >> 7; int co = (f & 127) << 2;
        pf[q] = *(const float4*)(xb + (size_t)k * HW + co);
    }

    float acc[8][8];
    #pragma unroll
    for (int i = 0; i < 8; ++i)
        #pragma unroll
        for (int j = 0; j < 8; ++j) acc[i][j] = 0.f;

    int wb = 0;
    for (int c0 = 0; c0 < CC; c0 += KB) {
        #pragma unroll
        for (int q = 0; q < 4; ++q) {
            int f = t + 256 * q; int k = f >> 7; int co = (f & 127) << 2;
            *(float4*)&xs[wb][k][co] = pf[q];
        }
        if (c0 + KB < CC) {
            #pragma unroll
            for (int q = 0; q < 4; ++q) {
                int f = t + 256 * q; int k = f >> 7; int co = (f & 127) << 2;
                pf[q] = *(const float4*)(xb + (size_t)(c0 + KB + k) * HW + co);
            }
        }
        // hoisted W loads for the whole chunk (uniform addr -> s_load batch)
        float4 wq2[2][8];
        #pragma unroll
        for (int half = 0; half < 2; ++half)
            #pragma unroll
            for (int i = 0; i < 8; ++i)
                wq2[half][i] = *(const float4*)(Wb + (size_t)i * CC + c0 + half * 4);
        __syncthreads();
        #pragma unroll
        for (int half = 0; half < 2; ++half) {
            #pragma unroll
            for (int kk = 0; kk < 4; ++kk) {
                int k = half * 4 + kk;
                float4 xa = *(const float4*)&xs[wb][k][tx * 4];
                float4 xc = *(const float4*)&xs[wb][k][256 + tx * 4];
                #pragma unroll
                for (int i = 0; i < 8; ++i) {
                    float w = ((const float*)&wq2[half][i])[kk];
                    acc[i][0] = fmaf(w, xa.x, acc[i][0]);
                    acc[i][1] = fmaf(w, xa.y, acc[i][1]);
                    acc[i][2] = fmaf(w, xa.z, acc[i][2]);
                    acc[i][3] = fmaf(w, xa.w, acc[i][3]);
                    acc[i][4] = fmaf(w, xc.x, acc[i][4]);
                    acc[i][5] = fmaf(w, xc.y, acc[i][5]);
                    acc[i][6] = fmaf(w, xc.z, acc[i][6]);
                    acc[i][7] = fmaf(w, xc.w, acc[i][7]);
                }
            }
        }
        __syncthreads();
        wb ^= 1;
    }

    #pragma unroll
    for (int i = 0; i < 8; ++i) {
        float* hp = h + ((size_t)(b * CC + o0 + ty * 8 + i)) * HW + hw0 + tx * 4;
        *(float4*)hp         = make_float4(acc[i][0], acc[i][1], acc[i][2], acc[i][3]);
        *(float4*)(hp + 256) = make_float4(acc[i][4], acc[i][5], acc[i][6], acc[i][7]);
    }
    #pragma unroll
    for (int i = 0; i < 8; ++i) {
        float s = 0.f, q = 0.f;
        #pragma unroll
        for (int j = 0; j < 8; ++j) { s += acc[i][j]; q = fmaf(acc[i][j], acc[i][j], q); }
        #pragma unroll
        for (int off = 1; off < 64; off <<= 1) {
            s += __shfl_xor(s, off);
            q += __shfl_xor(q, off);
        }
        if (tx == 0) {
            atomicAdd(&psum[o0 + ty * 8 + i], s);
            atomicAdd(&psumsq[o0 + ty * 8 + i], q);
        }
    }
}

// ---------------------------------------------------------------------------
__global__ void gu_bnfin(const float* __restrict__ psum, const float* __restrict__ psumsq,
                         const float* __restrict__ gamma, const float* __restrict__ beta,
                         float* __restrict__ avec, float* __restrict__ dvec)
{
    int c = threadIdx.x;
    const float invN = 1.f / 131072.f;
    float mu  = psum[c] * invN;
    float var = psumsq[c] * invN - mu * mu;
    float a   = gamma[c] * rsqrtf(var + 1e-5f);
    avec[c] = a;
    dvec[c] = beta[c] - mu * a;
}

// ---------------------------------------------------------------------------
// W_conv split -> bf16 hi/lo, layout [o][c] (K-contiguous)
// ---------------------------------------------------------------------------
__global__ __launch_bounds__(256)
void gu_wsplit(const float* __restrict__ Wc, unsigned short* __restrict__ Whi,
               unsigned short* __restrict__ Wlo)
{
    int i = blockIdx.x * 256 + threadIdx.x;   // 0..65535
    float w = Wc[i];
    unsigned short hh = f2bf(w);
    Whi[i] = hh;
    Wlo[i] = f2bf(w - bf2f(hh));
}

// ---------------------------------------------------------------------------
// r = relu(a*h+d) split -> bf16 hi/lo, TRANSPOSED layout rT[n][c]
// ---------------------------------------------------------------------------
__global__ __launch_bounds__(256)
void gu_split(const float* __restrict__ h, const float* __restrict__ avec,
              const float* __restrict__ dvec, unsigned short* __restrict__ rhiT,
              unsigned short* __restrict__ rloT)
{
    __shared__ float s_a[CC], s_d[CC];
    int t = threadIdx.x;
    s_a[t] = avec[t]; s_d[t] = dvec[t];
    __syncthreads();

    int n  = blockIdx.x * 256 + t;      // 0..131071
    int b  = n >> 14;
    int hw = n & (HW - 1);
    const float* hb = h + (size_t)b * CC * HW + hw;
    unsigned short* ph = rhiT + (size_t)n * CC;
    unsigned short* pl = rloT + (size_t)n * CC;

    for (int c0 = 0; c0 < CC; c0 += 8) {
        unsigned short vh[8], vl[8];
        #pragma unroll
        for (int e = 0; e < 8; ++e) {
            float v = hb[(size_t)(c0 + e) * HW];
            float r = fmaxf(fmaf(s_a[c0 + e], v, s_d[c0 + e]), 0.f);
            unsigned short hh = f2bf(r);
            vh[e] = hh;
            vl[e] = f2bf(r - bf2f(hh));
        }
        *(u16x8*)&ph[c0] = *(u16x8*)vh;
        *(u16x8*)&pl[c0] = *(u16x8*)vl;
    }
}

// ---------------------------------------------------------------------------
// Projection pass (unchanged, reads fp32 h -> bit-exact mask path)
// ---------------------------------------------------------------------------
__global__ __launch_bounds__(256)
void gu_proj(const float* __restrict__ h, const float* __restrict__ Wm,
             const float* __restrict__ Wsd, const float* __restrict__ avec,
             const float* __restrict__ dvec, const float* __restrict__ eps1,
             const float* __restrict__ eps50, float* __restrict__ prob_x,
             float* __restrict__ u0)
{
    __shared__ float s_a[CC], s_d[CC], s_m[CC], s_v[CC];
    int t = threadIdx.x;
    s_a[t] = avec[t]; s_d[t] = dvec[t]; s_m[t] = Wm[t]; s_v[t] = Wsd[t];
    __syncthreads();

    int p  = blockIdx.x * 256 + t;
    int b  = p >> 14;
    int hw = p & (HW - 1);
    const float* hb = h + (size_t)b * CC * HW + hw;

    float mp = 0.f, lp = 0.f;
    #pragma unroll 8
    for (int c = 0; c < CC; ++c) {
        float v = hb[(size_t)c * HW];
        float r = fmaxf(fmaf(s_a[c], v, s_d[c]), 0.f);
        mp = fmaf(s_m[c], r, mp);
        lp = fmaf(s_v[c], r, lp);
    }
    float std = expf(0.5f * lp);
    prob_x[p] = fmaf(eps1[p], std, mp);

    const float* e5 = eps50 + (size_t)b * 50 * HW + hw;
    double s = 0.0, q = 0.0;
    #pragma unroll 5
    for (int k = 0; k < 50; ++k) {
        float z = fmaf(e5[(size_t)k * HW], std, mp);
        float pr = 1.f / (1.f + expf(-z));
        s += (double)pr;
        q += (double)pr * (double)pr;
    }
    u0[p] = (float)((q - s * s * (1.0 / 50.0)) * (1.0 / 49.0));
}

// ---------------------------------------------------------------------------
// Box filter x3 + global min/max (unchanged)
// ---------------------------------------------------------------------------
__global__ __launch_bounds__(1024)
void gu_box(const float* __restrict__ u0, float* __restrict__ u3,
            unsigned* __restrict__ mnb, unsigned* __restrict__ mxb)
{
    __shared__ float A[HW];
    int b = blockIdx.x, t = threadIdx.x;
    const float* src = u0 + (size_t)b * HW;
    for (int i = t; i < HW; i += 1024) A[i] = src[i];
    __syncthreads();

    float tmp[16];
    for (int pass = 0; pass < 3; ++pass) {
        #pragma unroll
        for (int ii = 0; ii < 16; ++ii) {
            int i = t + ii * 1024;
            int r = i >> 7, c = i & 127;
            float s = 0.f;
            #pragma unroll
            for (int d = -3; d <= 3; ++d) {
                int cc = c + d;
                if (cc >= 0 && cc < 128) s += A[(r << 7) + cc];
            }
            tmp[ii] = s;
        }
        __syncthreads();
        #pragma unroll
        for (int ii = 0; ii < 16; ++ii) A[t + ii * 1024] = tmp[ii];
        __syncthreads();
        #pragma unroll
        for (int ii = 0; ii < 16; ++ii) {
            int i = t + ii * 1024;
            int r = i >> 7, c = i & 127;
            float s = 0.f;
            #pragma unroll
            for (int d = -3; d <= 3; ++d) {
                int rr = r + d;
                if (rr >= 0 && rr < 128) s += A[(rr << 7) + c];
            }
            tmp[ii] = s;
        }
        __syncthreads();
        #pragma unroll
        for (int ii = 0; ii < 16; ++ii) A[t + ii * 1024] = tmp[ii];
        __syncthreads();
    }

    float mn = 3.4e38f, mx = 0.f;
    for (int i = t; i < HW; i += 1024) {
        float v = A[i];
        u3[(size_t)b * HW + i] = v;
        mn = fminf(mn, v); mx = fmaxf(mx, v);
    }
    #pragma unroll
    for (int off = 1; off < 64; off <<= 1) {
        mn = fminf(mn, __shfl_xor(mn, off));
        mx = fmaxf(mx, __shfl_xor(mx, off));
    }
    if ((t & 63) == 0) {
        atomicMin(mnb, __float_as_uint(mn));
        atomicMax(mxb, __float_as_uint(mx));
    }
}

// ---------------------------------------------------------------------------
// GEMM2 MFMA: residual = W_conv * r via bf16 split-3 (hi*hi + hi*lo + lo*hi)
// 128(o) x 128(n) block tile, 4 waves x (64x64), 16x16x32 bf16 MFMA
// LDS XOR-swizzle: 16B chunk ^= (row&7), involution on write and read sides
// ---------------------------------------------------------------------------
__global__ __launch_bounds__(256)
void gu_gemm2m(const unsigned short* __restrict__ Whi, const unsigned short* __restrict__ Wlo,
               const unsigned short* __restrict__ rhiT, const unsigned short* __restrict__ rloT,
               const float* __restrict__ bconv, const float* __restrict__ u3,
               const unsigned* __restrict__ mnb, const unsigned* __restrict__ mxb,
               const float* __restrict__ ru, float* __restrict__ outr)
{
    __shared__ unsigned short Wh[128 * 64], Wl[128 * 64];
    __shared__ unsigned short Rh[128 * 64], Rl[128 * 64];

    const int t   = threadIdx.x;
    const int l   = t & 63;
    const int wid = t >> 6;           // 0..3
    const int wo  = (wid & 1) * 64;   // wave o-offset
    const int wn  = (wid >> 1) * 64;  // wave n-offset
    const int n0  = blockIdx.x * 128;
    const int o0  = blockIdx.y * 128;
    const int b   = n0 >> 14;
    const int hw0 = n0 & (HW - 1);

    f32x4 acc[4][4];
    #pragma unroll
    for (int m = 0; m < 4; ++m)
        #pragma unroll
        for (int nn = 0; nn < 4; ++nn) acc[m][nn] = (f32x4){0.f, 0.f, 0.f, 0.f};

    for (int kt = 0; kt < 4; ++kt) {
        const int c0 = kt * 64;
        #pragma unroll
        for (int q = 0; q < 4; ++q) {
            int chunk = t + 256 * q;              // 0..1023
            int row = chunk >> 3, ch = chunk & 7;
            int dst = row * 64 + ((ch ^ (row & 7)) << 3);       // ushort idx
            size_t wsrc = (size_t)(o0 + row) * 256 + c0 + (ch << 3);
            size_t rsrc = (size_t)(n0 + row) * 256 + c0 + (ch << 3);
            *(u16x8*)&Wh[dst] = *(const u16x8*)&Whi[wsrc];
            *(u16x8*)&Wl[dst] = *(const u16x8*)&Wlo[wsrc];
            *(u16x8*)&Rh[dst] = *(const u16x8*)&rhiT[rsrc];
            *(u16x8*)&Rl[dst] = *(const u16x8*)&rloT[rsrc];
        }
        __syncthreads();
        #pragma unroll
        for (int ks = 0; ks < 2; ++ks) {
            bf16x8 ah[4], al[4], bh[4], bl[4];
            #pragma unroll
            for (int m = 0; m < 4; ++m) {
                int row = wo + m * 16 + (l & 15);
                int idx = row * 64 + ((((ks << 2) + (l >> 4)) ^ (row & 7)) << 3);
                ah[m] = *(const bf16x8*)&Wh[idx];
                al[m] = *(const bf16x8*)&Wl[idx];
            }
            #pragma unroll
            for (int nn = 0; nn < 4; ++nn) {
                int row = wn + nn * 16 + (l & 15);
                int idx = row * 64 + ((((ks << 2) + (l >> 4)) ^ (row & 7)) << 3);
                bh[nn] = *(const bf16x8*)&Rh[idx];
                bl[nn] = *(const bf16x8*)&Rl[idx];
            }
            #pragma unroll
            for (int m = 0; m < 4; ++m)
                #pragma unroll
                for (int nn = 0; nn < 4; ++nn) {
                    acc[m][nn] = __builtin_amdgcn_mfma_f32_16x16x32_bf16(ah[m], bh[nn], acc[m][nn], 0, 0, 0);
                    acc[m][nn] = __builtin_amdgcn_mfma_f32_16x16x32_bf16(ah[m], bl[nn], acc[m][nn], 0, 0, 0);
                    acc[m][nn] = __builtin_amdgcn_mfma_f32_16x16x32_bf16(al[m], bh[nn], acc[m][nn], 0, 0, 0);
                }
        }
        __syncthreads();
    }

    // epilogue: mask/scale per n, bias per o; D layout col(n)=l&15, row(o)=(l>>4)*4+j
    float mn = __uint_as_float(*mnb);
    float mx = __uint_as_float(*mxb);
    float den = mx - mn;
    float scv[4];
    #pragma unroll
    for (int nn = 0; nn < 4; ++nn) {
        int hw = hw0 + wn + nn * 16 + (l & 15);
        float un = (u3[(size_t)b * HW + hw] - mn) / den;
        scv[nn] = (un < ru[(size_t)b * HW + hw]) ? (1.f - un) : 0.f;
    }
    #pragma unroll
    for (int m = 0; m < 4; ++m) {
        int obase = o0 + wo + m * 16 + (l >> 4) * 4;
        #pragma unroll
        for (int j = 0; j < 4; ++j) {
            float bc = bconv[obase + j];
            #pragma unroll
            for (int nn = 0; nn < 4; ++nn) {
                int hw = hw0 + wn + nn * 16 + (l & 15);
                outr[((size_t)(b * 256 + obase + j)) * HW + hw] = (acc[m][nn][j] + bc) * scv[nn];
            }
        }
    }
}

// ---------------------------------------------------------------------------
// GEMM2 fp32 fallback — used only if ws_size too small (same W-hoist applied)
// ---------------------------------------------------------------------------
__global__ __launch_bounds__(256)
void gu_gemm2(const float* __restrict__ h, const float* __restrict__ Wc,
              const float* __restrict__ bconv, const float* __restrict__ avec,
              const float* __restrict__ dvec, const float* __restrict__ u3,
              const unsigned* __restrict__ mnb, const unsigned* __restrict__ mxb,
              const float* __restrict__ ru, float* __restrict__ outr)
{
    __shared__ float xs[2][KB][NT];
    __shared__ float sa[CC], sd[CC];

    const int t  = threadIdx.x;
    const int tx = t & 63, ty = t >> 6;
    const int tyu = __builtin_amdgcn_readfirstlane(ty);
    const int o0 = blockIdx.y * OT;
    const int n0 = blockIdx.x * NT;
    const int b  = n0 >> 14;
    const int hw0 = n0 & (HW - 1);
    const float* xb = h + ((size_t)b * CC) * HW + hw0;
    const float* Wb = Wc + (size_t)(o0 + tyu * 8) * CC;

    sa[t] = avec[t]; sd[t] = dvec[t];

    float4 pf[4];
    #pragma unroll
    for (int q = 0; q < 4; ++q) {
        int f = t + 256 * q; int k = f >> 7; int co = (f & 127) << 2;
        pf[q] = *(const float4*)(xb + (size_t)k * HW + co);
    }

    float acc[8][8];
    #pragma unroll
    for (int i = 0; i < 8; ++i)
        #pragma unroll
        for (int j = 0; j < 8; ++j) acc[i][j] = 0.f;

    __syncthreads();
    int wb = 0;
    for (int c0 = 0; c0 < CC; c0 += KB) {
        #pragma unroll
        for (int q = 0; q < 4; ++q) {
            int f = t + 256 * q; int k = f >> 7; int co = (f & 127) << 2;
            float a = sa[c0 + k], d = sd[c0 + k];
            float4 v = pf[q];
            v.x = fmaxf(fmaf(a, v.x, d), 0.f);
            v.y = fmaxf(fmaf(a, v.y, d), 0.f);
            v.z = fmaxf(fmaf(a, v.z, d), 0.f);
            v.w = fmaxf(fmaf(a, v.w, d), 0.f);
            *(float4*)&xs[wb][k][co] = v;
        }
        if (c0 + KB < CC) {
            #pragma unroll
            for (int q = 0; q < 4; ++q) {
                int f = t + 256 * q; int k = f >> 7; int co = (f & 127) << 2;
                pf[q] = *(const float4*)(xb + (size_t)(c0 + KB + k) * HW + co);
            }
        }
        float4 wq2[2][8];
        #pragma unroll
        for (int half = 0; half < 2; ++half)
            #pragma unroll
            for (int i = 0; i < 8; ++i)
                wq2[half][i] = *(const float4*)(Wb + (size_t)i * CC + c0 + half * 4);
        __syncthreads();
        #pragma unroll
        for (int half = 0; half < 2; ++half) {
            #pragma unroll
            for (int kk = 0; kk < 4; ++kk) {
                int k = half * 4 + kk;
                float4 xa = *(const float4*)&xs[wb][k][tx * 4];
                float4 xc = *(const float4*)&xs[wb][k][256 + tx * 4];
                #pragma unroll
                for (int i = 0; i < 8; ++i) {
                    float w = ((const float*)&wq2[half][i])[kk];
                    acc[i][0] = fmaf(w, xa.x, acc[i][0]);
                    acc[i][1] = fmaf(w, xa.y, acc[i][1]);
                    acc[i][2] = fmaf(w, xa.z, acc[i][2]);
                    acc[i][3] = fmaf(w, xa.w, acc[i][3]);
                    acc[i][4] = fmaf(w, xc.x, acc[i][4]);
                    acc[i][5] = fmaf(w, xc.y, acc[i][5]);
                    acc[i][6] = fmaf(w, xc.z, acc[i][6]);
                    acc[i][7] = fmaf(w, xc.w, acc[i][7]);
                }
            }
        }
        __syncthreads();
        wb ^= 1;
    }

    float mn = __uint_as_float(*mnb);
    float mx = __uint_as_float(*mxb);
    float den = mx - mn;
    const float* u3b = u3 + (size_t)b * HW + hw0 + tx * 4;
    const float* rub = ru + (size_t)b * HW + hw0 + tx * 4;
    float sc[8];
    #pragma unroll
    for (int j = 0; j < 8; ++j) {
        int off = (j < 4) ? j : 256 + (j - 4);
        float un = (u3b[off] - mn) / den;
        sc[j] = (un < rub[off]) ? (1.f - un) : 0.f;
    }
    #pragma unroll
    for (int i = 0; i < 8; ++i) {
        float bc = bconv[o0 + ty * 8 + i];
        float* op = outr + ((size_t)(b * CC + o0 + ty * 8 + i)) * HW + hw0 + tx * 4;
        *(float4*)op = make_float4((acc[i][0] + bc) * sc[0], (acc[i][1] + bc) * sc[1],
                                   (acc[i][2] + bc) * sc[2], (acc[i][3] + bc) * sc[3]);
        *(float4*)(op + 256) = make_float4((acc[i][4] + bc) * sc[4], (acc[i][5] + bc) * sc[5],
                                           (acc[i][6] + bc) * sc[6], (acc[i][7] + bc) * sc[7]);
    }
}

// ---------------------------------------------------------------------------
extern "C" void kernel_launch(void* const* d_in, const int* in_sizes, int n_in,
                              void* d_out, int out_size, void* d_ws, size_t ws_size,
                              hipStream_t stream)
{
    const float* x     = (const float*)d_in[0];
    const float* Wp    = (const float*)d_in[1];
    const float* gamma = (const float*)d_in[2];
    const float* beta  = (const float*)d_in[3];
    const float* Wc    = (const float*)d_in[4];
    const float* bconv = (const float*)d_in[5];
    const float* Wm    = (const float*)d_in[6];
    const float* Wsd   = (const float*)d_in[7];
    const float* eps1  = (const float*)d_in[8];
    const float* eps50 = (const float*)d_in[9];
    const float* ru    = (const float*)d_in[10];

    float* outr = (float*)d_out;                    // residual: 8*256*128*128
    float* outp = outr + (size_t)33554432;          // prob_x:   8*128*128

    float* ws = (float*)d_ws;
    float* h  = ws;                                  // 33,554,432 floats (134MB)
    const size_t S = (size_t)33554432;
    float*    psum   = ws + S;
    float*    psumsq = ws + S + 256;
    float*    avec   = ws + S + 512;
    float*    dvec   = ws + S + 768;
    unsigned* mnb    = (unsigned*)(ws + S + 1024);
    unsigned* mxb    = (unsigned*)(ws + S + 1025);
    float*    u0     = ws + S + 2048;                // 131072
    float*    u3     = u0 + 131072;                  // 131072
    // bf16 split region: after u3
    unsigned short* rhiT = (unsigned short*)(ws + S + 264192);   // 33,554,432 u16
    unsigned short* rloT = rhiT + (size_t)33554432;              // 33,554,432 u16
    unsigned short* Whi  = rloT + (size_t)33554432;              // 65536 u16
    unsigned short* Wlo  = Whi + 65536;

    const size_t WS_NEED = (size_t)(S + 264192) * 4 + (size_t)134479872;
    const bool use_mfma = (ws_size >= WS_NEED);

    hipMemsetAsync(psum, 0, 512 * sizeof(float), stream);
    hipMemsetAsync(mnb, 0x7f, 4, stream);
    hipMemsetAsync(mxb, 0, 4, stream);

    gu_gemm1<<<dim3(256, 8), 256, 0, stream>>>(x, Wp, h, psum, psumsq);
    gu_bnfin<<<1, 256, 0, stream>>>(psum, psumsq, gamma, beta, avec, dvec);
    if (use_mfma) {
        gu_wsplit<<<256, 256, 0, stream>>>(Wc, Whi, Wlo);
        gu_split<<<512, 256, 0, stream>>>(h, avec, dvec, rhiT, rloT);
    }
    gu_proj<<<512, 256, 0, stream>>>(h, Wm, Wsd, avec, dvec, eps1, eps50, outp, u0);
    gu_box<<<8, 1024, 0, stream>>>(u0, u3, mnb, mxb);
    if (use_mfma) {
        gu_gemm2m<<<dim3(1024, 2), 256, 0, stream>>>(Whi, Wlo, rhiT, rloT, bconv,
                                                     u3, mnb, mxb, ru, outr);
    } else {
        gu_gemm2<<<dim3(256, 8), 256, 0, stream>>>(h, Wc, bconv, avec, dvec,
                                                   u3, mnb, mxb, ru, outr);
    }
}

// Round 9
// 644.229 us; speedup vs baseline: 1.6110x; 1.6110x over previous
//
#include <hip/hip_runtime.h>

#define HW   16384
#define CC   256
#define OT   32      // fp32 fallback tiling
#define NT   512
#define KB   8

typedef float          f32x4  __attribute__((ext_vector_type(4)));
typedef short          bf16x8 __attribute__((ext_vector_type(8)));
typedef unsigned short u16x8  __attribute__((ext_vector_type(8)));

__device__ inline unsigned short f2bf(float x) {     // RNE float->bf16
    unsigned u = __float_as_uint(x);
    u += 0x7FFFu + ((u >> 16) & 1u);
    return (unsigned short)(u >> 16);
}
__device__ inline float bf2f(unsigned short h) {
    return __uint_as_float(((unsigned)h) << 16);
}

// ===========================================================================
// MFMA PATH
// ===========================================================================

// ---------------------------------------------------------------------------
// x [c][n] fp32 -> xhiT/xloT [n][c] bf16 (transpose via LDS).
// Block: 64 n x 256 c. Grid 2048.
// ---------------------------------------------------------------------------
__global__ __launch_bounds__(256)
void gu_xsplit(const float* __restrict__ x, unsigned short* __restrict__ xhiT,
               unsigned short* __restrict__ xloT)
{
    __shared__ float T[64][257];
    const int t = threadIdx.x;
    const int l = t & 63, w = t >> 6;
    const int n0 = blockIdx.x * 64;          // 64 | 16384 -> no image straddle
    const int b  = n0 >> 14;
    const int hw0 = n0 & (HW - 1);
    const float* xb = x + (size_t)b * CC * HW + hw0;

    // load: wave w covers c in [w*64, w*64+64); float2 per lane
    #pragma unroll 4
    for (int it = 0; it < 32; ++it) {
        int cl = it * 2 + (l >> 5);          // 0..63
        int c  = w * 64 + cl;
        int nn = (l & 31) * 2;
        float2 v = *(const float2*)(xb + (size_t)c * HW + nn);
        T[nn][c]     = v.x;
        T[nn + 1][c] = v.y;
    }
    __syncthreads();

    // store: i covers 64 rows x 32 chunks of 8c
    #pragma unroll
    for (int it = 0; it < 8; ++it) {
        int i = it * 256 + t;
        int row = i >> 5, ch = i & 31;
        unsigned short vh[8], vl[8];
        #pragma unroll
        for (int e = 0; e < 8; ++e) {
            float v = T[row][ch * 8 + e];
            unsigned short hh = f2bf(v);
            vh[e] = hh;
            vl[e] = f2bf(v - bf2f(hh));
        }
        size_t dst = (size_t)(n0 + row) * CC + ch * 8;
        *(u16x8*)&xhiT[dst] = *(u16x8*)vh;
        *(u16x8*)&xloT[dst] = *(u16x8*)vl;
    }
}

// ---------------------------------------------------------------------------
// Split W_proj and W_conv -> bf16 hi/lo (both [o][c], K-contiguous)
// ---------------------------------------------------------------------------
__global__ __launch_bounds__(256)
void gu_wsplit2(const float* __restrict__ Wp, const float* __restrict__ Wc,
                unsigned short* __restrict__ Wphi, unsigned short* __restrict__ Wplo,
                unsigned short* __restrict__ Wchi, unsigned short* __restrict__ Wclo)
{
    int i = blockIdx.x * 256 + threadIdx.x;   // 0..131071
    if (i < 65536) {
        float w = Wp[i];
        unsigned short hh = f2bf(w);
        Wphi[i] = hh;
        Wplo[i] = f2bf(w - bf2f(hh));
    } else {
        int j = i - 65536;
        float w = Wc[j];
        unsigned short hh = f2bf(w);
        Wchi[j] = hh;
        Wclo[j] = f2bf(w - bf2f(hh));
    }
}

// ---------------------------------------------------------------------------
// GEMM1 MFMA: h = W_proj * x via split-3 (Whi*xhi + Whi*xlo + Wlo*xhi),
// fused BN stats. 128o x 128n tile, 4 waves x (64x64), 16x16x32 bf16.
// LDS XOR-swizzle (16B chunk ^= row&7) on write and read.
// ---------------------------------------------------------------------------
__global__ __launch_bounds__(256)
void gu_gemm1m(const unsigned short* __restrict__ xhiT, const unsigned short* __restrict__ xloT,
               const unsigned short* __restrict__ Wphi, const unsigned short* __restrict__ Wplo,
               float* __restrict__ h, float* __restrict__ psum, float* __restrict__ psumsq)
{
    __shared__ unsigned short Wh[128 * 64], Wl[128 * 64];
    __shared__ unsigned short Xh[128 * 64], Xl[128 * 64];
    __shared__ float sredS[128], sredQ[128];

    const int t   = threadIdx.x;
    const int l   = t & 63;
    const int wid = t >> 6;
    const int wo  = (wid & 1) * 64;
    const int wn  = (wid >> 1) * 64;
    const int n0  = blockIdx.x * 128;
    const int o0  = blockIdx.y * 128;
    const int b   = n0 >> 14;
    const int hw0 = n0 & (HW - 1);

    f32x4 acc[4][4];
    #pragma unroll
    for (int m = 0; m < 4; ++m)
        #pragma unroll
        for (int nn = 0; nn < 4; ++nn) acc[m][nn] = (f32x4){0.f, 0.f, 0.f, 0.f};

    for (int kt = 0; kt < 4; ++kt) {
        const int c0 = kt * 64;
        #pragma unroll
        for (int q = 0; q < 4; ++q) {
            int chunk = t + 256 * q;
            int row = chunk >> 3, ch = chunk & 7;
            int dst = row * 64 + ((ch ^ (row & 7)) << 3);
            size_t wsrc = (size_t)(o0 + row) * CC + c0 + (ch << 3);
            size_t xsrc = (size_t)(n0 + row) * CC + c0 + (ch << 3);
            *(u16x8*)&Wh[dst] = *(const u16x8*)&Wphi[wsrc];
            *(u16x8*)&Wl[dst] = *(const u16x8*)&Wplo[wsrc];
            *(u16x8*)&Xh[dst] = *(const u16x8*)&xhiT[xsrc];
            *(u16x8*)&Xl[dst] = *(const u16x8*)&xloT[xsrc];
        }
        __syncthreads();
        #pragma unroll
        for (int ks = 0; ks < 2; ++ks) {
            bf16x8 ah[4], al[4], bh[4], bl[4];
            #pragma unroll
            for (int m = 0; m < 4; ++m) {
                int row = wo + m * 16 + (l & 15);
                int idx = row * 64 + ((((ks << 2) + (l >> 4)) ^ (row & 7)) << 3);
                ah[m] = *(const bf16x8*)&Wh[idx];
                al[m] = *(const bf16x8*)&Wl[idx];
            }
            #pragma unroll
            for (int nn = 0; nn < 4; ++nn) {
                int row = wn + nn * 16 + (l & 15);
                int idx = row * 64 + ((((ks << 2) + (l >> 4)) ^ (row & 7)) << 3);
                bh[nn] = *(const bf16x8*)&Xh[idx];
                bl[nn] = *(const bf16x8*)&Xl[idx];
            }
            #pragma unroll
            for (int m = 0; m < 4; ++m)
                #pragma unroll
                for (int nn = 0; nn < 4; ++nn) {
                    acc[m][nn] = __builtin_amdgcn_mfma_f32_16x16x32_bf16(ah[m], bh[nn], acc[m][nn], 0, 0, 0);
                    acc[m][nn] = __builtin_amdgcn_mfma_f32_16x16x32_bf16(ah[m], bl[nn], acc[m][nn], 0, 0, 0);
                    acc[m][nn] = __builtin_amdgcn_mfma_f32_16x16x32_bf16(al[m], bh[nn], acc[m][nn], 0, 0, 0);
                }
        }
        __syncthreads();
    }

    // epilogue: store h (D layout col(n)=l&15, row(o)=(l>>4)*4+j) + BN stats
    float sst[4][4], qst[4][4];
    #pragma unroll
    for (int m = 0; m < 4; ++m) {
        int ob = wo + m * 16 + ((l >> 4) << 2);     // local o (0..127), +j
        #pragma unroll
        for (int j = 0; j < 4; ++j) {
            float s = 0.f, qq = 0.f;
            #pragma unroll
            for (int nn = 0; nn < 4; ++nn) {
                float v = acc[m][nn][j];
                h[((size_t)(b * CC + o0 + ob + j)) * HW + hw0 + wn + nn * 16 + (l & 15)] = v;
                s += v; qq = fmaf(v, v, qq);
            }
            #pragma unroll
            for (int off = 1; off < 16; off <<= 1) {
                s  += __shfl_xor(s, off);
                qq += __shfl_xor(qq, off);
            }
            sst[m][j] = s; qst[m][j] = qq;
            if (wn == 0 && (l & 15) == 0) { sredS[ob + j] = s; sredQ[ob + j] = qq; }
        }
    }
    __syncthreads();
    if (wn == 64 && (l & 15) == 0) {
        #pragma unroll
        for (int m = 0; m < 4; ++m) {
            int ob = wo + m * 16 + ((l >> 4) << 2);
            #pragma unroll
            for (int j = 0; j < 4; ++j) {
                atomicAdd(&psum[o0 + ob + j],   sst[m][j] + sredS[ob + j]);
                atomicAdd(&psumsq[o0 + ob + j], qst[m][j] + sredQ[ob + j]);
            }
        }
    }
}

// ---------------------------------------------------------------------------
// BN finalize
// ---------------------------------------------------------------------------
__global__ void gu_bnfin(const float* __restrict__ psum, const float* __restrict__ psumsq,
                         const float* __restrict__ gamma, const float* __restrict__ beta,
                         float* __restrict__ avec, float* __restrict__ dvec)
{
    int c = threadIdx.x;
    const float invN = 1.f / 131072.f;
    float mu  = psum[c] * invN;
    float var = psumsq[c] * invN - mu * mu;
    float a   = gamma[c] * rsqrtf(var + 1e-5f);
    avec[c] = a;
    dvec[c] = beta[c] - mu * a;
}

// ---------------------------------------------------------------------------
// Fused proj + r-split: mp/lp projections (bit-identical order to gu_proj),
// prob_x, 50-sample sigmoid variance -> u0, and rT[n][c] single bf16.
// ---------------------------------------------------------------------------
__global__ __launch_bounds__(256)
void gu_projsplit(const float* __restrict__ h, const float* __restrict__ Wm,
                  const float* __restrict__ Wsd, const float* __restrict__ avec,
                  const float* __restrict__ dvec, const float* __restrict__ eps1,
                  const float* __restrict__ eps50, float* __restrict__ prob_x,
                  float* __restrict__ u0, unsigned short* __restrict__ rT)
{
    __shared__ float s_a[CC], s_d[CC], s_m[CC], s_v[CC];
    int t = threadIdx.x;
    s_a[t] = avec[t]; s_d[t] = dvec[t]; s_m[t] = Wm[t]; s_v[t] = Wsd[t];
    __syncthreads();

    int p  = blockIdx.x * 256 + t;
    int b  = p >> 14;
    int hw = p & (HW - 1);
    const float* hb = h + (size_t)b * CC * HW + hw;
    unsigned short* pr = rT + (size_t)p * CC;

    float mp = 0.f, lp = 0.f;
    for (int c0 = 0; c0 < CC; c0 += 8) {
        unsigned short v8[8];
        #pragma unroll
        for (int e = 0; e < 8; ++e) {
            float v = hb[(size_t)(c0 + e) * HW];
            float r = fmaxf(fmaf(s_a[c0 + e], v, s_d[c0 + e]), 0.f);
            mp = fmaf(s_m[c0 + e], r, mp);
            lp = fmaf(s_v[c0 + e], r, lp);
            v8[e] = f2bf(r);
        }
        *(u16x8*)&pr[c0] = *(u16x8*)v8;
    }
    float std = expf(0.5f * lp);
    prob_x[p] = fmaf(eps1[p], std, mp);

    const float* e5 = eps50 + (size_t)b * 50 * HW + hw;
    double s = 0.0, q = 0.0;
    #pragma unroll 5
    for (int k = 0; k < 50; ++k) {
        float z = fmaf(e5[(size_t)k * HW], std, mp);
        float pr2 = 1.f / (1.f + expf(-z));
        s += (double)pr2;
        q += (double)pr2 * (double)pr2;
    }
    u0[p] = (float)((q - s * s * (1.0 / 50.0)) * (1.0 / 49.0));
}

// ---------------------------------------------------------------------------
// Box filter x3 + global min/max (unchanged)
// ---------------------------------------------------------------------------
__global__ __launch_bounds__(1024)
void gu_box(const float* __restrict__ u0, float* __restrict__ u3,
            unsigned* __restrict__ mnb, unsigned* __restrict__ mxb)
{
    __shared__ float A[HW];
    int b = blockIdx.x, t = threadIdx.x;
    const float* src = u0 + (size_t)b * HW;
    for (int i = t; i < HW; i += 1024) A[i] = src[i];
    __syncthreads();

    float tmp[16];
    for (int pass = 0; pass < 3; ++pass) {
        #pragma unroll
        for (int ii = 0; ii < 16; ++ii) {
            int i = t + ii * 1024;
            int r = i >> 7, c = i & 127;
            float s = 0.f;
            #pragma unroll
            for (int d = -3; d <= 3; ++d) {
                int cc = c + d;
                if (cc >= 0 && cc < 128) s += A[(r << 7) + cc];
            }
            tmp[ii] = s;
        }
        __syncthreads();
        #pragma unroll
        for (int ii = 0; ii < 16; ++ii) A[t + ii * 1024] = tmp[ii];
        __syncthreads();
        #pragma unroll
        for (int ii = 0; ii < 16; ++ii) {
            int i = t + ii * 1024;
            int r = i >> 7, c = i & 127;
            float s = 0.f;
            #pragma unroll
            for (int d = -3; d <= 3; ++d) {
                int rr = r + d;
                if (rr >= 0 && rr < 128) s += A[(rr << 7) + c];
            }
            tmp[ii] = s;
        }
        __syncthreads();
        #pragma unroll
        for (int ii = 0; ii < 16; ++ii) A[t + ii * 1024] = tmp[ii];
        __syncthreads();
    }

    float mn = 3.4e38f, mx = 0.f;
    for (int i = t; i < HW; i += 1024) {
        float v = A[i];
        u3[(size_t)b * HW + i] = v;
        mn = fminf(mn, v); mx = fmaxf(mx, v);
    }
    #pragma unroll
    for (int off = 1; off < 64; off <<= 1) {
        mn = fminf(mn, __shfl_xor(mn, off));
        mx = fmaxf(mx, __shfl_xor(mx, off));
    }
    if ((t & 63) == 0) {
        atomicMin(mnb, __float_as_uint(mn));
        atomicMax(mxb, __float_as_uint(mx));
    }
}

// ---------------------------------------------------------------------------
// GEMM2 MFMA: residual = W_conv * r via W-split-2 (Whi*r + Wlo*r), r single bf16.
// Same tile/swizzle as gemm1m. LDS 48KB.
// ---------------------------------------------------------------------------
__global__ __launch_bounds__(256)
void gu_gemm2m(const unsigned short* __restrict__ Wchi, const unsigned short* __restrict__ Wclo,
               const unsigned short* __restrict__ rT, const float* __restrict__ bconv,
               const float* __restrict__ u3, const unsigned* __restrict__ mnb,
               const unsigned* __restrict__ mxb, const float* __restrict__ ru,
               float* __restrict__ outr)
{
    __shared__ unsigned short Wh[128 * 64], Wl[128 * 64], Rh[128 * 64];

    const int t   = threadIdx.x;
    const int l   = t & 63;
    const int wid = t >> 6;
    const int wo  = (wid & 1) * 64;
    const int wn  = (wid >> 1) * 64;
    const int n0  = blockIdx.x * 128;
    const int o0  = blockIdx.y * 128;
    const int b   = n0 >> 14;
    const int hw0 = n0 & (HW - 1);

    f32x4 acc[4][4];
    #pragma unroll
    for (int m = 0; m < 4; ++m)
        #pragma unroll
        for (int nn = 0; nn < 4; ++nn) acc[m][nn] = (f32x4){0.f, 0.f, 0.f, 0.f};

    for (int kt = 0; kt < 4; ++kt) {
        const int c0 = kt * 64;
        #pragma unroll
        for (int q = 0; q < 4; ++q) {
            int chunk = t + 256 * q;
            int row = chunk >> 3, ch = chunk & 7;
            int dst = row * 64 + ((ch ^ (row & 7)) << 3);
            size_t wsrc = (size_t)(o0 + row) * CC + c0 + (ch << 3);
            size_t rsrc = (size_t)(n0 + row) * CC + c0 + (ch << 3);
            *(u16x8*)&Wh[dst] = *(const u16x8*)&Wchi[wsrc];
            *(u16x8*)&Wl[dst] = *(const u16x8*)&Wclo[wsrc];
            *(u16x8*)&Rh[dst] = *(const u16x8*)&rT[rsrc];
        }
        __syncthreads();
        #pragma unroll
        for (int ks = 0; ks < 2; ++ks) {
            bf16x8 ah[4], al[4], bh[4];
            #pragma unroll
            for (int m = 0; m < 4; ++m) {
                int row = wo + m * 16 + (l & 15);
                int idx = row * 64 + ((((ks << 2) + (l >> 4)) ^ (row & 7)) << 3);
                ah[m] = *(const bf16x8*)&Wh[idx];
                al[m] = *(const bf16x8*)&Wl[idx];
            }
            #pragma unroll
            for (int nn = 0; nn < 4; ++nn) {
                int row = wn + nn * 16 + (l & 15);
                int idx = row * 64 + ((((ks << 2) + (l >> 4)) ^ (row & 7)) << 3);
                bh[nn] = *(const bf16x8*)&Rh[idx];
            }
            #pragma unroll
            for (int m = 0; m < 4; ++m)
                #pragma unroll
                for (int nn = 0; nn < 4; ++nn) {
                    acc[m][nn] = __builtin_amdgcn_mfma_f32_16x16x32_bf16(ah[m], bh[nn], acc[m][nn], 0, 0, 0);
                    acc[m][nn] = __builtin_amdgcn_mfma_f32_16x16x32_bf16(al[m], bh[nn], acc[m][nn], 0, 0, 0);
                }
        }
        __syncthreads();
    }

    float mn = __uint_as_float(*mnb);
    float mx = __uint_as_float(*mxb);
    float den = mx - mn;
    float scv[4];
    #pragma unroll
    for (int nn = 0; nn < 4; ++nn) {
        int hw = hw0 + wn + nn * 16 + (l & 15);
        float un = (u3[(size_t)b * HW + hw] - mn) / den;
        scv[nn] = (un < ru[(size_t)b * HW + hw]) ? (1.f - un) : 0.f;
    }
    #pragma unroll
    for (int m = 0; m < 4; ++m) {
        int obase = o0 + wo + m * 16 + ((l >> 4) << 2);
        #pragma unroll
        for (int j = 0; j < 4; ++j) {
            float bc = bconv[obase + j];
            #pragma unroll
            for (int nn = 0; nn < 4; ++nn) {
                int hw = hw0 + wn + nn * 16 + (l & 15);
                outr[((size_t)(b * CC + obase + j)) * HW + hw] = (acc[m][nn][j] + bc) * scv[nn];
            }
        }
    }
}

// ===========================================================================
// FP32 FALLBACK PATH (validated rounds 4-8) — used only if ws_size too small
// ===========================================================================
__global__ __launch_bounds__(256)
void gu_gemm1(const float* __restrict__ x, const float* __restrict__ Wp,
              float* __restrict__ h, float* __restrict__ psum,
              float* __restrict__ psumsq)
{
    __shared__ float xs[2][KB][NT];
    const int t  = threadIdx.x;
    const int tx = t & 63, ty = t >> 6;
    const int tyu = __builtin_amdgcn_readfirstlane(ty);
    const int o0 = blockIdx.y * OT;
    const int n0 = blockIdx.x * NT;
    const int b  = n0 >> 14;
    const int hw0 = n0 & (HW - 1);
    const float* xb = x + ((size_t)b * CC) * HW + hw0;
    const float* Wb = Wp + (size_t)(o0 + tyu * 8) * CC;

    float4 pf[4];
    #pragma unroll
    for (int q = 0; q < 4; ++q) {
        int f = t + 256 * q; int k = f >> 7; int co = (f & 127) << 2;
        pf[q] = *(const float4*)(xb + (size_t)k * HW + co);
    }
    float acc[8][8];
    #pragma unroll
    for (int i = 0; i < 8; ++i)
        #pragma unroll
        for (int j = 0; j < 8; ++j) acc[i][j] = 0.f;

    int wb = 0;
    for (int c0 = 0; c0 < CC; c0 += KB) {
        #pragma unroll
        for (int q = 0; q < 4; ++q) {
            int f = t + 256 * q; int k = f >> 7; int co = (f & 127) << 2;
            *(float4*)&xs[wb][k][co] = pf[q];
        }
        if (c0 + KB < CC) {
            #pragma unroll
            for (int q = 0; q < 4; ++q) {
                int f = t + 256 * q; int k = f >> 7; int co = (f & 127) << 2;
                pf[q] = *(const float4*)(xb + (size_t)(c0 + KB + k) * HW + co);
            }
        }
        __syncthreads();
        #pragma unroll
        for (int half = 0; half < 2; ++half) {
            float4 wq[8];
            #pragma unroll
            for (int i = 0; i < 8; ++i)
                wq[i] = *(const float4*)(Wb + (size_t)i * CC + c0 + half * 4);
            #pragma unroll
            for (int kk = 0; kk < 4; ++kk) {
                int k = half * 4 + kk;
                float4 xa = *(const float4*)&xs[wb][k][tx * 4];
                float4 xc = *(const float4*)&xs[wb][k][256 + tx * 4];
                #pragma unroll
                for (int i = 0; i < 8; ++i) {
                    float w = ((const float*)&wq[i])[kk];
                    acc[i][0] = fmaf(w, xa.x, acc[i][0]);
                    acc[i][1] = fmaf(w, xa.y, acc[i][1]);
                    acc[i][2] = fmaf(w, xa.z, acc[i][2]);
                    acc[i][3] = fmaf(w, xa.w, acc[i][3]);
                    acc[i][4] = fmaf(w, xc.x, acc[i][4]);
                    acc[i][5] = fmaf(w, xc.y, acc[i][5]);
                    acc[i][6] = fmaf(w, xc.z, acc[i][6]);
                    acc[i][7] = fmaf(w, xc.w, acc[i][7]);
                }
            }
        }
        __syncthreads();
        wb ^= 1;
    }
    #pragma unroll
    for (int i = 0; i < 8; ++i) {
        float* hp = h + ((size_t)(b * CC + o0 + ty * 8 + i)) * HW + hw0 + tx * 4;
        *(float4*)hp         = make_float4(acc[i][0], acc[i][1], acc[i][2], acc[i][3]);
        *(float4*)(hp + 256) = make_float4(acc[i][4], acc[i][5], acc[i][6], acc[i][7]);
    }
    #pragma unroll
    for (int i = 0; i < 8; ++i) {
        float s = 0.f, q = 0.f;
        #pragma unroll
        for (int j = 0; j < 8; ++j) { s += acc[i][j]; q = fmaf(acc[i][j], acc[i][j], q); }
        #pragma unroll
        for (int off = 1; off < 64; off <<= 1) {
            s += __shfl_xor(s, off);
            q += __shfl_xor(q, off);
        }
        if (tx == 0) {
            atomicAdd(&psum[o0 + ty * 8 + i], s);
            atomicAdd(&psumsq[o0 + ty * 8 + i], q);
        }
    }
}

__global__ __launch_bounds__(256)
void gu_proj(const float* __restrict__ h, const float* __restrict__ Wm,
             const float* __restrict__ Wsd, const float* __restrict__ avec,
             const float* __restrict__ dvec, const float* __restrict__ eps1,
             const float* __restrict__ eps50, float* __restrict__ prob_x,
             float* __restrict__ u0)
{
    __shared__ float s_a[CC], s_d[CC], s_m[CC], s_v[CC];
    int t = threadIdx.x;
    s_a[t] = avec[t]; s_d[t] = dvec[t]; s_m[t] = Wm[t]; s_v[t] = Wsd[t];
    __syncthreads();
    int p  = blockIdx.x * 256 + t;
    int b  = p >> 14;
    int hw = p & (HW - 1);
    const float* hb = h + (size_t)b * CC * HW + hw;
    float mp = 0.f, lp = 0.f;
    #pragma unroll 8
    for (int c = 0; c < CC; ++c) {
        float v = hb[(size_t)c * HW];
        float r = fmaxf(fmaf(s_a[c], v, s_d[c]), 0.f);
        mp = fmaf(s_m[c], r, mp);
        lp = fmaf(s_v[c], r, lp);
    }
    float std = expf(0.5f * lp);
    prob_x[p] = fmaf(eps1[p], std, mp);
    const float* e5 = eps50 + (size_t)b * 50 * HW + hw;
    double s = 0.0, q = 0.0;
    #pragma unroll 5
    for (int k = 0; k < 50; ++k) {
        float z = fmaf(e5[(size_t)k * HW], std, mp);
        float pr = 1.f / (1.f + expf(-z));
        s += (double)pr;
        q += (double)pr * (double)pr;
    }
    u0[p] = (float)((q - s * s * (1.0 / 50.0)) * (1.0 / 49.0));
}

__global__ __launch_bounds__(256)
void gu_gemm2(const float* __restrict__ h, const float* __restrict__ Wc,
              const float* __restrict__ bconv, const float* __restrict__ avec,
              const float* __restrict__ dvec, const float* __restrict__ u3,
              const unsigned* __restrict__ mnb, const unsigned* __restrict__ mxb,
              const float* __restrict__ ru, float* __restrict__ outr)
{
    __shared__ float xs[2][KB][NT];
    __shared__ float sa[CC], sd[CC];
    const int t  = threadIdx.x;
    const int tx = t & 63, ty = t >> 6;
    const int tyu = __builtin_amdgcn_readfirstlane(ty);
    const int o0 = blockIdx.y * OT;
    const int n0 = blockIdx.x * NT;
    const int b  = n0 >> 14;
    const int hw0 = n0 & (HW - 1);
    const float* xb = h + ((size_t)b * CC) * HW + hw0;
    const float* Wb = Wc + (size_t)(o0 + tyu * 8) * CC;

    sa[t] = avec[t]; sd[t] = dvec[t];
    float4 pf[4];
    #pragma unroll
    for (int q = 0; q < 4; ++q) {
        int f = t + 256 * q; int k = f >> 7; int co = (f & 127) << 2;
        pf[q] = *(const float4*)(xb + (size_t)k * HW + co);
    }
    float acc[8][8];
    #pragma unroll
    for (int i = 0; i < 8; ++i)
        #pragma unroll
        for (int j = 0; j < 8; ++j) acc[i][j] = 0.f;

    __syncthreads();
    int wb = 0;
    for (int c0 = 0; c0 < CC; c0 += KB) {
        #pragma unroll
        for (int q = 0; q < 4; ++q) {
            int f = t + 256 * q; int k = f >> 7; int co = (f & 127) << 2;
            float a = sa[c0 + k], d = sd[c0 + k];
            float4 v = pf[q];
            v.x = fmaxf(fmaf(a, v.x, d), 0.f);
            v.y = fmaxf(fmaf(a, v.y, d), 0.f);
            v.z = fmaxf(fmaf(a, v.z, d), 0.f);
            v.w = fmaxf(fmaf(a, v.w, d), 0.f);
            *(float4*)&xs[wb][k][co] = v;
        }
        if (c0 + KB < CC) {
            #pragma unroll
            for (int q = 0; q < 4; ++q) {
                int f = t + 256 * q; int k = f >> 7; int co = (f & 127) << 2;
                pf[q] = *(const float4*)(xb + (size_t)(c0 + KB + k) * HW + co);
            }
        }
        __syncthreads();
        #pragma unroll
        for (int half = 0; half < 2; ++half) {
            float4 wq[8];
            #pragma unroll
            for (int i = 0; i < 8; ++i)
                wq[i] = *(const float4*)(Wb + (size_t)i * CC + c0 + half * 4);
            #pragma unroll
            for (int kk = 0; kk < 4; ++kk) {
                int k = half * 4 + kk;
                float4 xa = *(const float4*)&xs[wb][k][tx * 4];
                float4 xc = *(const float4*)&xs[wb][k][256 + tx * 4];
                #pragma unroll
                for (int i = 0; i < 8; ++i) {
                    float w = ((const float*)&wq[i])[kk];
                    acc[i][0] = fmaf(w, xa.x, acc[i][0]);
                    acc[i][1] = fmaf(w, xa.y, acc[i][1]);
                    acc[i][2] = fmaf(w, xa.z, acc[i][2]);
                    acc[i][3] = fmaf(w, xa.w, acc[i][3]);
                    acc[i][4] = fmaf(w, xc.x, acc[i][4]);
                    acc[i][5] = fmaf(w, xc.y, acc[i][5]);
                    acc[i][6] = fmaf(w, xc.z, acc[i][6]);
                    acc[i][7] = fmaf(w, xc.w, acc[i][7]);
                }
            }
        }
        __syncthreads();
        wb ^= 1;
    }
    float mn = __uint_as_float(*mnb);
    float mx = __uint_as_float(*mxb);
    float den = mx - mn;
    const float* u3b = u3 + (size_t)b * HW + hw0 + tx * 4;
    const float* rub = ru + (size_t)b * HW + hw0 + tx * 4;
    float sc[8];
    #pragma unroll
    for (int j = 0; j < 8; ++j) {
        int off = (j < 4) ? j : 256 + (j - 4);
        float un = (u3b[off] - mn) / den;
        sc[j] = (un < rub[off]) ? (1.f - un) : 0.f;
    }
    #pragma unroll
    for (int i = 0; i < 8; ++i) {
        float bc = bconv[o0 + ty * 8 + i];
        float* op = outr + ((size_t)(b * CC + o0 + ty * 8 + i)) * HW + hw0 + tx * 4;
        *(float4*)op = make_float4((acc[i][0] + bc) * sc[0], (acc[i][1] + bc) * sc[1],
                                   (acc[i][2] + bc) * sc[2], (acc[i][3] + bc) * sc[3]);
        *(float4*)(op + 256) = make_float4((acc[i][4] + bc) * sc[4], (acc[i][5] + bc) * sc[5],
                                           (acc[i][6] + bc) * sc[6], (acc[i][7] + bc) * sc[7]);
    }
}

// ---------------------------------------------------------------------------
extern "C" void kernel_launch(void* const* d_in, const int* in_sizes, int n_in,
                              void* d_out, int out_size, void* d_ws, size_t ws_size,
                              hipStream_t stream)
{
    const float* x     = (const float*)d_in[0];
    const float* Wp    = (const float*)d_in[1];
    const float* gamma = (const float*)d_in[2];
    const float* beta  = (const float*)d_in[3];
    const float* Wc    = (const float*)d_in[4];
    const float* bconv = (const float*)d_in[5];
    const float* Wm    = (const float*)d_in[6];
    const float* Wsd   = (const float*)d_in[7];
    const float* eps1  = (const float*)d_in[8];
    const float* eps50 = (const float*)d_in[9];
    const float* ru    = (const float*)d_in[10];

    float* outr = (float*)d_out;                    // residual: 33,554,432 f32
    float* outp = outr + (size_t)33554432;          // prob_x

    float* ws = (float*)d_ws;
    float* h  = ws;                                  // 33,554,432 f32
    const size_t S = (size_t)33554432;
    float*    psum   = ws + S;
    float*    psumsq = ws + S + 256;
    float*    avec   = ws + S + 512;
    float*    dvec   = ws + S + 768;
    unsigned* mnb    = (unsigned*)(ws + S + 1024);
    unsigned* mxb    = (unsigned*)(ws + S + 1025);
    float*    u0     = ws + S + 2048;                // 131072
    float*    u3     = u0 + 131072;                  // 131072
    unsigned short* rT   = (unsigned short*)(ws + S + 264192);  // 33,554,432 u16
    unsigned short* Wphi = rT + (size_t)33554432;               // 65536 each
    unsigned short* Wplo = Wphi + 65536;
    unsigned short* Wchi = Wplo + 65536;
    unsigned short* Wclo = Wchi + 65536;

    // x-transpose scratch lives in d_out's residual region (dead until gemm2m)
    unsigned short* xhiT = (unsigned short*)d_out;              // 33,554,432 u16
    unsigned short* xloT = xhiT + (size_t)33554432;

    const size_t WS_NEED = (size_t)(S + 264192) * 4 + (size_t)33554432 * 2 + 4 * 65536 * 2;
    const bool use_mfma = (ws_size >= WS_NEED);

    hipMemsetAsync(psum, 0, 512 * sizeof(float), stream);
    hipMemsetAsync(mnb, 0x7f, 4, stream);
    hipMemsetAsync(mxb, 0, 4, stream);

    if (use_mfma) {
        gu_xsplit<<<2048, 256, 0, stream>>>(x, xhiT, xloT);
        gu_wsplit2<<<512, 256, 0, stream>>>(Wp, Wc, Wphi, Wplo, Wchi, Wclo);
        gu_gemm1m<<<dim3(1024, 2), 256, 0, stream>>>(xhiT, xloT, Wphi, Wplo, h, psum, psumsq);
        gu_bnfin<<<1, 256, 0, stream>>>(psum, psumsq, gamma, beta, avec, dvec);
        gu_projsplit<<<512, 256, 0, stream>>>(h, Wm, Wsd, avec, dvec, eps1, eps50, outp, u0, rT);
        gu_box<<<8, 1024, 0, stream>>>(u0, u3, mnb, mxb);
        gu_gemm2m<<<dim3(1024, 2), 256, 0, stream>>>(Wchi, Wclo, rT, bconv, u3, mnb, mxb, ru, outr);
    } else {
        gu_gemm1<<<dim3(256, 8), 256, 0, stream>>>(x, Wp, h, psum, psumsq);
        gu_bnfin<<<1, 256, 0, stream>>>(psum, psumsq, gamma, beta, avec, dvec);
        gu_proj<<<512, 256, 0, stream>>>(h, Wm, Wsd, avec, dvec, eps1, eps50, outp, u0);
        gu_box<<<8, 1024, 0, stream>>>(u0, u3, mnb, mxb);
        gu_gemm2<<<dim3(256, 8), 256, 0, stream>>>(h, Wc, bconv, avec, dvec, u3, mnb, mxb, ru, outr);
    }
}